// Round 2
// baseline (924.895 us; speedup 1.0000x reference)
//
#include <hip/hip_runtime.h>
#include <cstdint>

typedef float float2v __attribute__((ext_vector_type(2)));

__device__ inline float2v mk2(float a, float b) { float2v r; r[0] = a; r[1] = b; return r; }

__device__ inline float fast_exp2(float x) {
#if __has_builtin(__builtin_amdgcn_exp2f)
  return __builtin_amdgcn_exp2f(x);
#else
  return exp2f(x);
#endif
}
__device__ inline float fast_rcp(float x) {
#if __has_builtin(__builtin_amdgcn_rcpf)
  return __builtin_amdgcn_rcpf(x);
#else
  return 1.0f / x;
#endif
}

#define BB 256
#define SS 4096
#define II 32
#define HH 64
// Segmented scan (validated round 1: contractive recurrence, 32-step warmup
// error ~0.16^32 ~ 1e-25). This round: the input projection pre = x@Wc^T + bc
// is FUSED into the scan (the separate 210us gemm_pre kernel and its 256 MiB
// of pre write+read are deleted; pre is now exact fp32, no bf16 rounding).
// Scan restructured for latency: 4 streams per 256-thread block (beats the
// 1-wave-workgroup slot cap), CH=8 tanh ring, launch_bounds(256,3) so the
// W_hh row (64 VGPRs) + Wc row (32 VGPRs) stay register-resident (round-1
// kernel had VGPR_Count=60 -> W_hh was demoted to per-step reloads).
#define SEGS 32
#define SEGLEN 128
#define WU 32
#define CH 8
#define WPB 4  // streams (waves) per block

// ---------------- prep: Wc = W_ih @ W_in  [64][32], bc = W_ih@b_in + bias ----------------
__global__ __launch_bounds__(256) void prep_kernel(
    const float* __restrict__ W_in, const float* __restrict__ b_in,
    const float* __restrict__ W_ih, const float* __restrict__ bias,
    float* __restrict__ Wc, float* __restrict__ bc) {
  int tid = threadIdx.x;
  int j = tid & 63;
  int iq = tid >> 6;  // 0..3, each handles 8 of the 32 input cols
  float acc[8];
#pragma unroll
  for (int i = 0; i < 8; ++i) acc[i] = 0.f;
  const float* wih = W_ih + j * HH;
  for (int h = 0; h < HH; ++h) {
    float w = wih[h];
    const float* wr = W_in + h * II + iq * 8;
#pragma unroll
    for (int i = 0; i < 8; ++i) acc[i] = fmaf(w, wr[i], acc[i]);
  }
#pragma unroll
  for (int i = 0; i < 8; ++i) Wc[j * II + iq * 8 + i] = acc[i];
  if (iq == 0) {
    float s = 0.f;
    for (int h = 0; h < HH; ++h) s = fmaf(wih[h], b_in[h], s);
    bc[j] = s + bias[j];
  }
}

// ---------------- fused scan: input proj + recurrence + output GEMV ----------------
__global__ __launch_bounds__(256, 3) void fused_scan_kernel(
    const float* __restrict__ x, const float* __restrict__ Wc,
    const float* __restrict__ bc, const float* __restrict__ W_hh,
    const float* __restrict__ tau, const float* __restrict__ W_out,
    const float* __restrict__ b_out, float* __restrict__ out) {
  __shared__ __align__(16) float tbuf[WPB][CH * 68];  // per-wave tanh ring (8 steps x 64, +4 pad)
  __shared__ __align__(16) float woutl[64];
  int lane = threadIdx.x & 63;
  int w = threadIdx.x >> 6;
  int idx = blockIdx.x * WPB + w;  // stream id: 4 consecutive segments of one batch
  int b = idx >> 5;
  int s = idx & (SEGS - 1);
  int warmCh = s ? (WU / CH) : 0;       // 4 warmup chunks (0 for segment 0)
  int nCh = SEGLEN / CH + warmCh;       // 16 or 20
  long t0 = (long)s * SEGLEN - (s ? WU : 0);
  const float* xs = x + ((size_t)b * SS + (size_t)t0) * II;
  float* outb = out + (size_t)b * SS + (size_t)s * SEGLEN;

  // W_hh row for this lane's hidden unit: 32 float2 pairs (64 VGPRs, resident)
  float2v w2[32];
  {
    const float4* wr = (const float4*)(W_hh + lane * HH);
#pragma unroll
    for (int i = 0; i < 16; ++i) {
      float4 q = wr[i];
      w2[2 * i] = mk2(q.x, q.y);
      w2[2 * i + 1] = mk2(q.z, q.w);
    }
  }
  // Wc row (input projection weights): 16 float2 pairs (32 VGPRs, resident)
  float2v wc2[16];
  {
    const float4* wr = (const float4*)(Wc + lane * II);
#pragma unroll
    for (int i = 0; i < 8; ++i) {
      float4 q = wr[i];
      wc2[2 * i] = mk2(q.x, q.y);
      wc2[2 * i + 1] = mk2(q.z, q.w);
    }
  }
  float cinv = 1.0f / tau[lane];  // dt = 1.0
  float aco = 1.0f - cinv;
  float bcv = bc[lane];
  woutl[lane] = W_out[lane];  // all waves write identical values: benign
  float bout = b_out[0];
  float* tb = tbuf[w];
  tb[(CH - 1) * 68 + lane] = 0.0f;  // tanh(h_{t0-1}) = 0
  __syncthreads();

  float h = 0.0f;
  for (int c = 0; c < nCh; ++c) {
#pragma unroll
    for (int r = 0; r < CH; ++r) {
      // ---- input projection: x_t (wave-uniform row, 8x float4, L1-broadcast) . Wc[lane]
      const float4* xr = (const float4*)xs;
      float2v xa0 = mk2(0, 0), xa1 = mk2(0, 0), xa2 = mk2(0, 0), xa3 = mk2(0, 0);
#pragma unroll
      for (int i = 0; i < 8; i += 2) {
        float4 q = xr[i];
        float4 p = xr[i + 1];
        xa0 += mk2(q.x, q.y) * wc2[2 * i];
        xa1 += mk2(q.z, q.w) * wc2[2 * i + 1];
        xa2 += mk2(p.x, p.y) * wc2[2 * i + 2];
        xa3 += mk2(p.z, p.w) * wc2[2 * i + 3];
      }
      // ---- recurrent matvec: broadcast-read tanh(h_{t-1}) from the ring
      const float4* trow = (const float4*)(tb + ((r + CH - 1) & (CH - 1)) * 68);
      float2v a0 = mk2(0, 0), a1 = mk2(0, 0), a2 = mk2(0, 0), a3 = mk2(0, 0);
#pragma unroll
      for (int i = 0; i < 16; i += 2) {
        float4 q = trow[i];
        float4 p = trow[i + 1];
        a0 += mk2(q.x, q.y) * w2[2 * i];
        a1 += mk2(q.z, q.w) * w2[2 * i + 1];
        a2 += mk2(p.x, p.y) * w2[2 * i + 2];
        a3 += mk2(p.z, p.w) * w2[2 * i + 3];
      }
      float2v aa = ((a0 + a1) + (a2 + a3)) + ((xa0 + xa1) + (xa2 + xa3));
      float dot = aa[0] + aa[1];
      h = fmaf(aco, h, cinv * (dot + bcv));
      // tanh(h) = 1 - 2/(exp2(2*log2e*h)+1); saturates correctly at +/-inf
      float e = fast_exp2(h * 2.885390081777927f);
      float tv = 1.0f - 2.0f * fast_rcp(e + 1.0f);
      tb[r * 68 + lane] = tv;
      xs += II;
    }
    // ---- fused output GEMV for this chunk (skip warmup chunks)
    int rc = c - warmCh;
    if (rc >= 0) {
      int rr = lane & 7;   // step within chunk
      int g = lane >> 3;   // hidden octant
      const float4* tr = (const float4*)(tb + rr * 68 + g * 8);
      const float4* wl = (const float4*)(woutl + g * 8);
      float4 q0 = tr[0], q1 = tr[1];
      float4 u0 = wl[0], u1 = wl[1];
      float2v s0 = mk2(q0.x, q0.y) * mk2(u0.x, u0.y) + mk2(q0.z, q0.w) * mk2(u0.z, u0.w);
      s0 += mk2(q1.x, q1.y) * mk2(u1.x, u1.y) + mk2(q1.z, q1.w) * mk2(u1.z, u1.w);
      float v = s0[0] + s0[1];
      v += __shfl_xor(v, 8);
      v += __shfl_xor(v, 16);
      v += __shfl_xor(v, 32);
      if (lane < 8) outb[rc * CH + lane] = v + bout;
    }
  }
}

extern "C" void kernel_launch(void* const* d_in, const int* in_sizes, int n_in,
                              void* d_out, int out_size, void* d_ws, size_t ws_size,
                              hipStream_t stream) {
  const float* x     = (const float*)d_in[0];
  const float* W_in  = (const float*)d_in[1];
  const float* b_in  = (const float*)d_in[2];
  const float* W_hh  = (const float*)d_in[3];
  const float* W_ih  = (const float*)d_in[4];
  const float* bias  = (const float*)d_in[5];
  const float* tau   = (const float*)d_in[6];
  const float* W_out = (const float*)d_in[7];
  const float* b_out = (const float*)d_in[8];
  float* out = (float*)d_out;
  char* ws = (char*)d_ws;
  float* Wc = (float*)ws;            // 8 KB
  float* bc = (float*)(ws + 8192);   // 256 B

  hipLaunchKernelGGL(prep_kernel, dim3(1), dim3(256), 0, stream,
                     W_in, b_in, W_ih, bias, Wc, bc);
  hipLaunchKernelGGL(fused_scan_kernel, dim3(BB * SEGS / WPB), dim3(256), 0, stream,
                     x, Wc, bc, W_hh, tau, W_out, b_out, out);
}